// Round 2
// baseline (194.193 us; speedup 1.0000x reference)
//
#include <hip/hip_runtime.h>
#include <hip/hip_bf16.h>

#define BATCH   16384
#define NSTEPS  100
#define DT_     0.01f
#define SQRTDT  0.1f
#define SIGMA0_ 0.5f

typedef _Float16  f16x2  __attribute__((ext_vector_type(2)));
typedef _Float16  f16x4  __attribute__((ext_vector_type(4)));
typedef _Float16  f16x8  __attribute__((ext_vector_type(8)));
typedef __fp16    h16x2  __attribute__((ext_vector_type(2)));
typedef float     f32x4  __attribute__((ext_vector_type(4)));

typedef const __attribute__((address_space(1))) void* gas_ptr;
typedef __attribute__((address_space(3))) void*       las_ptr;

__global__ void zero_out_kernel(float* out) { if (threadIdx.x == 0) out[0] = 0.0f; }

static __device__ __forceinline__ f16x4 pk4(const f32x4& d) {
    union { h16x2 h[2]; f16x4 v; } c;
    c.h[0] = __builtin_amdgcn_cvt_pkrtz(d[0], d[1]);
    c.h[1] = __builtin_amdgcn_cvt_pkrtz(d[2], d[3]);
    return c.v;
}

// MLP-split version: each 16-path group is served by a PAIR of waves —
// a z-wave (z-MLP + epilogue + state) and a q-wave (q-MLP + its own bit-exact
// y-update). Waves double (1024 -> 2048, 2/SIMD) while total instruction
// count stays constant; cross-wave traffic is ONE float (q) per path per
// step through a double-buffered LDS slot + one s_barrier. Noise ring stays
// 4-deep in flight across barriers via counted vmcnt(3) (never drained to 0
// in the main loop). Replicated-row W3^T MFMA means the split is bit-exact:
// z lives in P[0..2], q in P[3], each from disjoint zero-padded A rows.
__launch_bounds__(256, 2)
__global__ void deepbsde_kernel(
    const float* __restrict__ y0,  const float* __restrict__ Y0,
    const float* __restrict__ zW1, const float* __restrict__ zb1,
    const float* __restrict__ zW2, const float* __restrict__ zb2,
    const float* __restrict__ zW3, const float* __restrict__ zb3,
    const float* __restrict__ qW1, const float* __restrict__ qb1,
    const float* __restrict__ qW2, const float* __restrict__ qb2,
    const float* __restrict__ qW3, const float* __restrict__ qb3,
    const float* __restrict__ dW,  const float* __restrict__ dZ,
    float* __restrict__ out)
{
    __shared__ __align__(16) char ring[2][8][384];   // [group][slot][16 paths * 24B]
    __shared__ float qx[2][2][16];                   // [buf][group][path] q exchange

    const int tid  = threadIdx.x;
    const int lane = tid & 63;
    const int w    = tid >> 6;        // 0..3
    const int g    = w & 1;           // path group within block
    const bool isQ = (w >= 2);        // waves 2,3 are q-waves
    const int ln15 = lane & 15, q4 = lane >> 4;
    const int gw   = (blockIdx.x << 1) + g;
    const int pbase = gw << 4;

    const float* W1p = isQ ? qW1 : zW1;
    const float* b1p = isQ ? qb1 : zb1;
    const float* W2p = isQ ? qW2 : zW2;
    const float* b2p = isQ ? qb2 : zb2;

    // ---- layer-1 consts as f16x2 pairs; pair m covers frag idx (2m,2m+1),
    //      k(idx) = 32*(idx>>3) + 8*q4 + (idx&7) ----
    f16x2 A1[8], B1[8], C1[8];
#pragma unroll
    for (int m = 0; m < 8; ++m) {
        int i0 = 2*m, i1 = 2*m + 1;
        int k0 = 32*(i0 >> 3) + 8*q4 + (i0 & 7);
        int k1 = 32*(i1 >> 3) + 8*q4 + (i1 & 7);
        A1[m] = (f16x2){(_Float16)W1p[k0],      (_Float16)W1p[k1]};
        B1[m] = (f16x2){(_Float16)W1p[64 + k0], (_Float16)W1p[64 + k1]};
        C1[m] = (f16x2){(_Float16)b1p[k0],      (_Float16)b1p[k1]};
    }

    // ---- resident W2^T A-frags in f16: A[n=16tN+ln15][k=32f+8q4+j] ----
    f16x8 Af[4][2];
#pragma unroll
    for (int tN = 0; tN < 4; ++tN)
#pragma unroll
        for (int f = 0; f < 2; ++f)
#pragma unroll
            for (int j = 0; j < 8; ++j) {
                int k = 32*f + 8*q4 + j, n = 16*tN + ln15;
                Af[tN][f][j] = (_Float16)W2p[k*64 + n];
            }

    // ---- layer-2 bias along Dt rows: row n = 16tN + 4q4 + r ----
    f32x4 b2v[4];
#pragma unroll
    for (int tN = 0; tN < 4; ++tN)
#pragma unroll
        for (int r = 0; r < 4; ++r)
            b2v[tN][r] = b2p[16*tN + 4*q4 + r];

    // ---- layer-3 W3^T A-frags, rows replicated across row-quads.
    //      z-wave: components 0..2 live (c3<3); q-wave: component 3 (c3==3).
    const int c3 = ln15 & 3;
    f16x4 A3[4];
#pragma unroll
    for (int tN = 0; tN < 4; ++tN)
#pragma unroll
        for (int j = 0; j < 4; ++j) {
            int n = 16*tN + 4*q4 + j;
            float wv = isQ ? ((c3 == 3) ? qW3[n]        : 0.0f)
                           : ((c3 < 3)  ? zW3[n*3 + c3] : 0.0f);
            A3[tN][j] = (_Float16)wv;
        }

    float y = y0[0], Yv = Y0[0], t = 0.0f, acc = 0.0f;
    const float zb30 = zb3[0], zb31 = zb3[1], zb32 = zb3[2], qb30 = qb3[0];

    const f16x2 zero2h = {(_Float16)0.0f, (_Float16)0.0f};
    const f32x4 zero4  = {0.0f, 0.0f, 0.0f, 0.0f};

    float z0 = 0.f, z1 = 0.f, z2 = 0.f;
    float nw0 = 0.f, nw1 = 0.f, nw2 = 0.f, nz0 = 0.f, nz1 = 0.f, nz2 = 0.f;

    auto fillz = [&](int i) {
        if (lane < 24) {
            const char* gp = (lane < 12)
                ? (const char*)dW + ((size_t)i * BATCH + pbase) * 12 + (size_t)lane * 16
                : (const char*)dZ + ((size_t)i * BATCH + pbase) * 12 + (size_t)(lane - 12) * 16;
            __builtin_amdgcn_global_load_lds((gas_ptr)gp, (las_ptr)&ring[g][i & 7][0],
                                             16, 0, 0);
        }
    };

    auto compute = [&](int i) {
        const float* sl = (const float*)&ring[g][i & 7][0];
        if (isQ) {
            // cross-wave (z-filled) data: volatile pins the reads after the barrier
            const volatile float* sv = (const volatile float*)sl;
            nw0 = sv[ln15*3 + 0]; nw1 = sv[ln15*3 + 1]; nw2 = sv[ln15*3 + 2];
        } else {
            nw0 = sl[ln15*3 + 0];      nw1 = sl[ln15*3 + 1];      nw2 = sl[ln15*3 + 2];
            nz0 = sl[48 + ln15*3 + 0]; nz1 = sl[48 + ln15*3 + 1]; nz2 = sl[48 + ln15*3 + 2];
        }

        // ---- h1, packed f16: result pairs ARE the B-frag halves ----
        _Float16 th = (_Float16)t, yh = (_Float16)y;
        const f16x2 tv = {th, th}, yv = {yh, yh};
        union { f16x2 h[4]; f16x8 v; } b0, b1;
#pragma unroll
        for (int m = 0; m < 8; ++m) {
            f16x2 h = __builtin_elementwise_max((f16x2)(B1[m]*yv + (A1[m]*tv + C1[m])), zero2h);
            if (m < 4) b0.h[m] = h; else b1.h[m - 4] = h;
        }

        // ---- layer-2: f16 MFMA, Dt[n][path]; relu -> f16 B-frags ----
        f16x4 B3[4];
#pragma unroll
        for (int tN = 0; tN < 4; ++tN) {
            f32x4 d = b2v[tN];
            d = __builtin_amdgcn_mfma_f32_16x16x32_f16(Af[tN][0], b0.v, d, 0, 0, 0);
            d = __builtin_amdgcn_mfma_f32_16x16x32_f16(Af[tN][1], b1.v, d, 0, 0, 0);
            B3[tN] = pk4(__builtin_elementwise_max(d, zero4));
        }

        // ---- layer-3: replicated-row A-frags -> role's P components on ALL lanes ----
        f32x4 P0 = zero4, P1 = zero4, P2 = zero4, P3 = zero4;
        P0 = __builtin_amdgcn_mfma_f32_16x16x16f16(A3[0], B3[0], P0, 0, 0, 0);
        P1 = __builtin_amdgcn_mfma_f32_16x16x16f16(A3[1], B3[1], P1, 0, 0, 0);
        P2 = __builtin_amdgcn_mfma_f32_16x16x16f16(A3[2], B3[2], P2, 0, 0, 0);
        P3 = __builtin_amdgcn_mfma_f32_16x16x16f16(A3[3], B3[3], P3, 0, 0, 0);
        f32x4 P = (P0 + P1) + (P2 + P3);

        if (isQ) {
            float qv = P[3] + qb30;
            if (q4 == 0) *(volatile float*)&qx[i & 1][g][ln15] = qv;
            // bit-exact replica of the z-wave's y update (same exprs, same inputs)
            float dw0 = SQRTDT*nw0, dw1 = SQRTDT*nw1, dw2 = SQRTDT*nw2;
            y = y + qv*DT_ + SIGMA0_*(dw0 + dw1 + dw2);
            t += DT_;
        } else {
            z0 = P[0] + zb30; z1 = P[1] + zb31; z2 = P[2] + zb32;
        }
    };

    auto post = [&](int i) {
        if (!isQ) {
            float qv = *(const volatile float*)&qx[i & 1][g][ln15];
            float dw0 = SQRTDT*nw0, dw1 = SQRTDT*nw1, dw2 = SQRTDT*nw2;
            float dz0 = SQRTDT*nz0, dz1 = SQRTDT*nz1, dz2 = SQRTDT*nz2;
            float zdw = fmaf(z2, dw2, fmaf(z1, dw1, z0*dw0));
            float zdz = fmaf(z2, dz2, fmaf(z1, dz1, z0*dz0));
            float f = 0.5f*qv*qv;
            Yv = Yv - f*DT_ + zdw;
            float r = zdw - zdz;
            acc = fmaf(r, r, acc);
            y = y + qv*DT_ + SIGMA0_*(dw0 + dw1 + dw2);
            t += DT_;
        }
    };

    // prologue: ring depth 4; ensure slot 0 complete + visible to q-waves
    if (!isQ) {
        fillz(0); fillz(1); fillz(2); fillz(3);
        __builtin_amdgcn_s_waitcnt(0x0F73);           // vmcnt(3): slot 0 done
    }
    __builtin_amdgcn_s_barrier();
    __builtin_amdgcn_sched_barrier(0);

#pragma unroll 1
    for (int i = 0; i < NSTEPS - 4; ++i) {
        if (!isQ) fillz(i + 4);
        compute(i);
        // lgkmcnt(0): q-write visible; vmcnt(3): slot i+1 done (q-wave: no-op)
        __builtin_amdgcn_s_waitcnt(0x0073);
        __builtin_amdgcn_s_barrier();
        __builtin_amdgcn_sched_barrier(0);
        post(i);
    }

    // tail: drain ring with decreasing counted vmcnt, keep q-exchange barriers
    compute(NSTEPS - 4);
    __builtin_amdgcn_s_waitcnt(0x0072);               // lgkm(0) + vmcnt(2)
    __builtin_amdgcn_s_barrier();
    __builtin_amdgcn_sched_barrier(0);
    post(NSTEPS - 4);

    compute(NSTEPS - 3);
    __builtin_amdgcn_s_waitcnt(0x0071);               // lgkm(0) + vmcnt(1)
    __builtin_amdgcn_s_barrier();
    __builtin_amdgcn_sched_barrier(0);
    post(NSTEPS - 3);

    compute(NSTEPS - 2);
    __builtin_amdgcn_s_waitcnt(0x0070);               // lgkm(0) + vmcnt(0)
    __builtin_amdgcn_s_barrier();
    __builtin_amdgcn_sched_barrier(0);
    post(NSTEPS - 2);

    compute(NSTEPS - 1);
    __builtin_amdgcn_s_waitcnt(0xC07F);               // lgkm(0)
    __builtin_amdgcn_s_barrier();
    __builtin_amdgcn_sched_barrier(0);
    post(NSTEPS - 1);

    if (!isQ) {
        float dterm = Yv - y*y;
        acc = fmaf(dterm, dterm, acc);
        // q4-replicas hold identical acc -> count q4==0 lanes only
        float val = (q4 == 0) ? acc : 0.0f;
#pragma unroll
        for (int off = 1; off < 64; off <<= 1) val += __shfl_xor(val, off);
        if (lane == 0) atomicAdd(out, val * (1.0f / BATCH));
    }
}

extern "C" void kernel_launch(void* const* d_in, const int* in_sizes, int n_in,
                              void* d_out, int out_size, void* d_ws, size_t ws_size,
                              hipStream_t stream)
{
    zero_out_kernel<<<1, 64, 0, stream>>>((float*)d_out);
    deepbsde_kernel<<<512, 256, 0, stream>>>(
        (const float*)d_in[0],  (const float*)d_in[1],
        (const float*)d_in[2],  (const float*)d_in[3],
        (const float*)d_in[4],  (const float*)d_in[5],
        (const float*)d_in[6],  (const float*)d_in[7],
        (const float*)d_in[8],  (const float*)d_in[9],
        (const float*)d_in[10], (const float*)d_in[11],
        (const float*)d_in[12], (const float*)d_in[13],
        (const float*)d_in[14], (const float*)d_in[15],
        (float*)d_out);
}

// Round 3
// 162.658 us; speedup vs baseline: 1.1939x; 1.1939x over previous
//
#include <hip/hip_runtime.h>
#include <hip/hip_bf16.h>

#define BATCH   16384
#define NSTEPS  100
#define DT_     0.01f
#define SQRTDT  0.1f
#define SIGMA0_ 0.5f

typedef _Float16  f16x2  __attribute__((ext_vector_type(2)));
typedef _Float16  f16x4  __attribute__((ext_vector_type(4)));
typedef _Float16  f16x8  __attribute__((ext_vector_type(8)));
typedef __fp16    h16x2  __attribute__((ext_vector_type(2)));
typedef float     f32x4  __attribute__((ext_vector_type(4)));

typedef const __attribute__((address_space(1))) void* gas_ptr;
typedef __attribute__((address_space(3))) void*       las_ptr;

__global__ void zero_out_kernel(float* out) { if (threadIdx.x == 0) out[0] = 0.0f; }

static __device__ __forceinline__ f16x4 pk4(const f32x4& d) {
    union { h16x2 h[2]; f16x4 v; } c;
    c.h[0] = __builtin_amdgcn_cvt_pkrtz(d[0], d[1]);
    c.h[1] = __builtin_amdgcn_cvt_pkrtz(d[2], d[3]);
    return c.v;
}

// Fused single-wave structure (R0) + instruction-diet round:
//  - Layer-3 z+q now 4 chained mfma_f32_16x16x32_f16 (was 8 x 16x16x16 +
//    12 v_add): A-frag n-permutation chosen so the B3[tN] f16x4 packs
//    concatenate directly into the 16x16x32 B-frag (k=8*q4+j ->
//    n = 16*(2f+(j>>2)) + 4*q4 + (j&3)); replicated rows mod 4 keep
//    P = (z0,z1,z2,q) valid on every lane.
//  - Layer-2 relu moved AFTER the f16 pack: max(pk4(d),0) in packed f16
//    (2 v_pk_max_f16 vs 4 v_max_f32). RTZ pack preserves sign => identical.
//  - SQRTDT folded into z-side W3/b3 (A-frag prescale) and into the
//    epilogue constants (sigma*sqrtdt, -0.5*dt): no per-step SQRTDT muls.
__launch_bounds__(256, 1)
__global__ void deepbsde_kernel(
    const float* __restrict__ y0,  const float* __restrict__ Y0,
    const float* __restrict__ zW1, const float* __restrict__ zb1,
    const float* __restrict__ zW2, const float* __restrict__ zb2,
    const float* __restrict__ zW3, const float* __restrict__ zb3,
    const float* __restrict__ qW1, const float* __restrict__ qb1,
    const float* __restrict__ qW2, const float* __restrict__ qb2,
    const float* __restrict__ qW3, const float* __restrict__ qb3,
    const float* __restrict__ dW,  const float* __restrict__ dZ,
    float* __restrict__ out)
{
    __shared__ __align__(16) char ring[4][8][384];   // [wave][slot][16 paths * 24B]

    const int tid  = threadIdx.x;
    const int lane = tid & 63;
    const int w    = tid >> 6;
    const int ln15 = lane & 15, q4 = lane >> 4;
    const int gw   = (blockIdx.x << 2) + w;
    const int pbase = gw << 4;

    // ---- layer-1 consts as f16x2 pairs; pair m covers frag idx (2m,2m+1),
    //      k(idx) = 32*(idx>>3) + 8*q4 + (idx&7) ----
    f16x2 A1z[8], B1z[8], C1z[8], A1q[8], B1q[8], C1q[8];
#pragma unroll
    for (int m = 0; m < 8; ++m) {
        int i0 = 2*m, i1 = 2*m + 1;
        int k0 = 32*(i0 >> 3) + 8*q4 + (i0 & 7);
        int k1 = 32*(i1 >> 3) + 8*q4 + (i1 & 7);
        A1z[m] = (f16x2){(_Float16)zW1[k0],      (_Float16)zW1[k1]};
        B1z[m] = (f16x2){(_Float16)zW1[64 + k0], (_Float16)zW1[64 + k1]};
        C1z[m] = (f16x2){(_Float16)zb1[k0],      (_Float16)zb1[k1]};
        A1q[m] = (f16x2){(_Float16)qW1[k0],      (_Float16)qW1[k1]};
        B1q[m] = (f16x2){(_Float16)qW1[64 + k0], (_Float16)qW1[64 + k1]};
        C1q[m] = (f16x2){(_Float16)qb1[k0],      (_Float16)qb1[k1]};
    }

    // ---- resident W2^T A-frags in f16: A[n=16tN+ln15][k=32f+8q4+j] ----
    f16x8 AfZ[4][2], AfQ[4][2];
#pragma unroll
    for (int tN = 0; tN < 4; ++tN)
#pragma unroll
        for (int f = 0; f < 2; ++f)
#pragma unroll
            for (int j = 0; j < 8; ++j) {
                int k = 32*f + 8*q4 + j, n = 16*tN + ln15;
                AfZ[tN][f][j] = (_Float16)zW2[k*64 + n];
                AfQ[tN][f][j] = (_Float16)qW2[k*64 + n];
            }

    // ---- layer-2 bias along Dt rows: row n = 16tN + 4q4 + r ----
    f32x4 b2zv[4], b2qv[4];
#pragma unroll
    for (int tN = 0; tN < 4; ++tN)
#pragma unroll
        for (int r = 0; r < 4; ++r) {
            b2zv[tN][r] = zb2[16*tN + 4*q4 + r];
            b2qv[tN][r] = qb2[16*tN + 4*q4 + r];
        }

    // ---- layer-3 combined A-frags for 16x16x32: f=0,1 -> z (SQRTDT-
    //      prescaled), f=2,3 -> q. Rows replicated mod 4 (c3 = ln15&3).
    //      Slot j at quad q4 maps to n = 16*(2*(f&1)+(j>>2)) + 4*q4 + (j&3),
    //      matching concat(B3[2f],B3[2f+1]) as the B-frag. ----
    const int c3 = ln15 & 3;
    f16x8 A3[4];
#pragma unroll
    for (int f = 0; f < 4; ++f)
#pragma unroll
        for (int j = 0; j < 8; ++j) {
            int tN = 2*(f & 1) + (j >> 2);
            int n  = 16*tN + 4*q4 + (j & 3);
            float wv = (f < 2) ? ((c3 < 3)  ? SQRTDT * zW3[n*3 + c3] : 0.0f)
                               : ((c3 == 3) ? qW3[n]                 : 0.0f);
            A3[f][j] = (_Float16)wv;
        }

    float y = y0[0], Yv = Y0[0], t = 0.0f, acc = 0.0f;
    const float zb30s = SQRTDT * zb3[0], zb31s = SQRTDT * zb3[1],
                zb32s = SQRTDT * zb3[2], qb30  = qb3[0];
    const float CSIG = SIGMA0_ * SQRTDT;       // diffusion coefficient
    const float NHDT = -0.5f * DT_;            // -f*dt factor

    const f16x2 zero2h = {(_Float16)0.0f, (_Float16)0.0f};
    const f16x4 zero4h = {(_Float16)0.0f, (_Float16)0.0f, (_Float16)0.0f, (_Float16)0.0f};
    const f32x4 zero4  = {0.0f, 0.0f, 0.0f, 0.0f};

    auto fill = [&](int i) {
        if (lane < 24) {
            const char* g = (lane < 12)
                ? (const char*)dW + ((size_t)i * BATCH + pbase) * 12 + (size_t)lane * 16
                : (const char*)dZ + ((size_t)i * BATCH + pbase) * 12 + (size_t)(lane - 12) * 16;
            __builtin_amdgcn_global_load_lds((gas_ptr)g, (las_ptr)&ring[w][i & 7][0],
                                             16, 0, 0);
        }
    };
    fill(0); fill(1); fill(2); fill(3);

    auto body = [&](int i) {
        const float* sl = (const float*)&ring[w][i & 7][0];
        float nw0 = sl[ln15*3 + 0], nw1 = sl[ln15*3 + 1], nw2 = sl[ln15*3 + 2];
        float nz0 = sl[48 + ln15*3 + 0], nz1 = sl[48 + ln15*3 + 1], nz2 = sl[48 + ln15*3 + 2];

        // ---- h1, packed f16: result pairs ARE the B-frag halves ----
        _Float16 th = (_Float16)t, yh = (_Float16)y;
        const f16x2 tv = {th, th}, yv = {yh, yh};
        union { f16x2 h[4]; f16x8 v; } bz0, bz1, bq0, bq1;
#pragma unroll
        for (int m = 0; m < 8; ++m) {
            f16x2 hz = __builtin_elementwise_max((f16x2)(B1z[m]*yv + (A1z[m]*tv + C1z[m])), zero2h);
            f16x2 hq = __builtin_elementwise_max((f16x2)(B1q[m]*yv + (A1q[m]*tv + C1q[m])), zero2h);
            if (m < 4) { bz0.h[m] = hz;     bq0.h[m] = hq; }
            else       { bz1.h[m - 4] = hz; bq1.h[m - 4] = hq; }
        }

        // ---- layer-2: f16 MFMA, Dt[n][path]; pack then packed relu ----
        union { f16x4 q[4]; f16x8 o[2]; } Bz, Bq;
#pragma unroll
        for (int tN = 0; tN < 4; ++tN) {
            f32x4 dz = b2zv[tN];
            dz = __builtin_amdgcn_mfma_f32_16x16x32_f16(AfZ[tN][0], bz0.v, dz, 0, 0, 0);
            dz = __builtin_amdgcn_mfma_f32_16x16x32_f16(AfZ[tN][1], bz1.v, dz, 0, 0, 0);
            f32x4 dq = b2qv[tN];
            dq = __builtin_amdgcn_mfma_f32_16x16x32_f16(AfQ[tN][0], bq0.v, dq, 0, 0, 0);
            dq = __builtin_amdgcn_mfma_f32_16x16x32_f16(AfQ[tN][1], bq1.v, dq, 0, 0, 0);
            Bz.q[tN] = __builtin_elementwise_max(pk4(dz), zero4h);
            Bq.q[tN] = __builtin_elementwise_max(pk4(dq), zero4h);
        }

        // ---- layer-3: two 2-chains of 16x16x32, P = (z0s,z1s,z2s,q) all lanes ----
        f32x4 Pz = zero4, Pq = zero4;
        Pz = __builtin_amdgcn_mfma_f32_16x16x32_f16(A3[0], Bz.o[0], Pz, 0, 0, 0);
        Pz = __builtin_amdgcn_mfma_f32_16x16x32_f16(A3[1], Bz.o[1], Pz, 0, 0, 0);
        Pq = __builtin_amdgcn_mfma_f32_16x16x32_f16(A3[2], Bq.o[0], Pq, 0, 0, 0);
        Pq = __builtin_amdgcn_mfma_f32_16x16x32_f16(A3[3], Bq.o[1], Pq, 0, 0, 0);
        f32x4 P = Pz + Pq;

        // ---- scalar epilogue (z pre-scaled by SQRTDT) ----
        float zs0 = P[0] + zb30s, zs1 = P[1] + zb31s, zs2 = P[2] + zb32s;
        float qv  = P[3] + qb30;

        float zdw = fmaf(zs2, nw2, fmaf(zs1, nw1, zs0*nw0));
        float zdz = fmaf(zs2, nz2, fmaf(zs1, nz1, zs0*nz0));
        float snw = (nw0 + nw1) + nw2;
        Yv = fmaf(NHDT*qv, qv, Yv) + zdw;
        float r = zdw - zdz;                       // residual: (Y - f*DT) cancels
        acc = fmaf(r, r, acc);
        y = fmaf(qv, DT_, y);
        y = fmaf(CSIG, snw, y);
        t += DT_;
    };

#pragma unroll 1
    for (int i = 0; i < NSTEPS - 4; ++i) {
        __builtin_amdgcn_s_waitcnt(0x0F73);   // vmcnt(3): slot i complete
        fill(i + 4);
        body(i);
    }
    __builtin_amdgcn_s_waitcnt(0x0F70);       // vmcnt(0): drain remaining fills
#pragma unroll 1
    for (int i = NSTEPS - 4; i < NSTEPS; ++i) body(i);

    float dterm = Yv - y*y;
    acc = fmaf(dterm, dterm, acc);

    // q4-replicas hold identical acc -> count q4==0 lanes only
    float val = (q4 == 0) ? acc : 0.0f;
#pragma unroll
    for (int off = 1; off < 64; off <<= 1) val += __shfl_xor(val, off);
    if (lane == 0) atomicAdd(out, val * (1.0f / BATCH));
}

extern "C" void kernel_launch(void* const* d_in, const int* in_sizes, int n_in,
                              void* d_out, int out_size, void* d_ws, size_t ws_size,
                              hipStream_t stream)
{
    zero_out_kernel<<<1, 64, 0, stream>>>((float*)d_out);
    deepbsde_kernel<<<256, 256, 0, stream>>>(
        (const float*)d_in[0],  (const float*)d_in[1],
        (const float*)d_in[2],  (const float*)d_in[3],
        (const float*)d_in[4],  (const float*)d_in[5],
        (const float*)d_in[6],  (const float*)d_in[7],
        (const float*)d_in[8],  (const float*)d_in[9],
        (const float*)d_in[10], (const float*)d_in[11],
        (const float*)d_in[12], (const float*)d_in[13],
        (const float*)d_in[14], (const float*)d_in[15],
        (float*)d_out);
}